// Round 1
// baseline (3177.470 us; speedup 1.0000x reference)
//
#include <hip/hip_runtime.h>
#include <math.h>

constexpr int NN = 50000;   // nodes
constexpr int NE = 800000;  // edges (without self loops)
constexpr int E2 = NE + NN; // with self loops
constexpr int NH = 8;       // heads

// ---------------------------------------------------------------------------
// degree count (real edges only; self-loop added in k_inv)
__global__ void k_count(const int* __restrict__ dst, float* __restrict__ cnt) {
  int i = blockIdx.x * blockDim.x + threadIdx.x;
  if (i < NE) atomicAdd(&cnt[dst[i]], 1.0f);
}

__global__ void k_inv(float* __restrict__ inv) {
  int i = blockIdx.x * blockDim.x + threadIdx.x;
  if (i < NN) inv[i] = 1.0f / (inv[i] + 1.0f);
}

// ---------------------------------------------------------------------------
// P[n, j] = sum_c X[n,c] * W[j,c]   (K = 64 fixed). 64 nodes / block.
template <int JDIM>
__global__ void k_gemm_xwt(const float* __restrict__ X, const float* __restrict__ W,
                           float* __restrict__ P) {
  __shared__ float xs[64][68];  // pad 68 to break bank conflicts
  const int t = threadIdx.x;
  const int nb = blockIdx.x * 64;

  // stage 64x64 x-tile (coalesced float4 loads)
#pragma unroll
  for (int r = 0; r < 4; ++r) {
    int flat = t + r * 256;   // float4 index in [0,1024)
    int nl = flat >> 4;
    int c4 = flat & 15;
    int n = nb + nl;
    float4 v = make_float4(0.f, 0.f, 0.f, 0.f);
    if (n < NN) v = reinterpret_cast<const float4*>(X)[(size_t)n * 16 + c4];
    xs[nl][c4 * 4 + 0] = v.x;
    xs[nl][c4 * 4 + 1] = v.y;
    xs[nl][c4 * 4 + 2] = v.z;
    xs[nl][c4 * 4 + 3] = v.w;
  }
  __syncthreads();

  const int nl = t >> 2;   // node within tile  (16 threads share... 4 j-lanes)
  const int jq = t & 3;
  const int n = nb + nl;
  const bool valid = n < NN;

  // hoist this thread's x row to registers
  const float4* xr4 = reinterpret_cast<const float4*>(xs[nl]);
  float4 xreg[16];
#pragma unroll
  for (int c4 = 0; c4 < 16; ++c4) xreg[c4] = xr4[c4];

  const float4* W4 = reinterpret_cast<const float4*>(W);
  for (int j = jq; j < JDIM; j += 4) {
    float acc = 0.f;
#pragma unroll
    for (int c4 = 0; c4 < 16; ++c4) {
      float4 w = W4[j * 16 + c4];
      acc = fmaf(xreg[c4].x, w.x, acc);
      acc = fmaf(xreg[c4].y, w.y, acc);
      acc = fmaf(xreg[c4].z, w.z, acc);
      acc = fmaf(xreg[c4].w, w.w, acc);
    }
    if (valid) P[(size_t)n * JDIM + j] = acc;
  }
}

// ---------------------------------------------------------------------------
// per-edge: softmax over heads, msg = sum_h a_h * P[src, h, :], scatter-add.
template <int COUT>
__global__ void k_edge(const int* __restrict__ src, const int* __restrict__ dst,
                       const float* __restrict__ q, const float* __restrict__ cvec,
                       const float* __restrict__ P, float* __restrict__ agg) {
  constexpr int EPW = 64 / COUT;  // edges per wave
  const int lane = threadIdx.x & 63;
  const long wid = ((long)blockIdx.x * blockDim.x + threadIdx.x) >> 6;
  const long e = wid * EPW + (COUT == 64 ? 0 : (lane >> 5));
  const int o = lane & (COUT - 1);
  if (e >= E2) return;

  int s, d;
  if (e < NE) { s = src[e]; d = dst[e]; }
  else        { s = d = (int)(e - NE); }

  const float4* q4 = reinterpret_cast<const float4*>(q);
  const float4* c4p = reinterpret_cast<const float4*>(cvec);
  float4 qd0 = q4[2 * d], qd1 = q4[2 * d + 1];
  float4 qs0 = q4[2 * s], qs1 = q4[2 * s + 1];
  float4 c0 = c4p[0], c1 = c4p[1];

  float l[8];
  l[0] = qd0.x - qs0.x + c0.x;  l[1] = qd0.y - qs0.y + c0.y;
  l[2] = qd0.z - qs0.z + c0.z;  l[3] = qd0.w - qs0.w + c0.w;
  l[4] = qd1.x - qs1.x + c1.x;  l[5] = qd1.y - qs1.y + c1.y;
  l[6] = qd1.z - qs1.z + c1.z;  l[7] = qd1.w - qs1.w + c1.w;

  float m = l[0];
#pragma unroll
  for (int h = 1; h < 8; ++h) m = fmaxf(m, l[h]);
  float sum = 0.f;
#pragma unroll
  for (int h = 0; h < 8; ++h) { l[h] = __expf(l[h] - m); sum += l[h]; }
  const float inv_s = 1.0f / sum;

  const float* Prow = P + (size_t)s * (NH * COUT) + o;
  float acc = 0.f;
#pragma unroll
  for (int h = 0; h < 8; ++h) acc = fmaf(l[h], Prow[h * COUT], acc);
  acc *= inv_s;

  atomicAdd(&agg[(size_t)d * COUT + o], acc);
}

// ---------------------------------------------------------------------------
// y = relu(agg*inv + b); accumulate per-channel sum/sumsq into stats[0..63]/[64..127]
__global__ void k_finalize_relu(const float* __restrict__ agg, const float* __restrict__ inv,
                                const float* __restrict__ b, float* __restrict__ y,
                                float* __restrict__ stats) {
  __shared__ float ssum[64], ssq[64];
  const int t = threadIdx.x;
  if (t < 64) { ssum[t] = 0.f; ssq[t] = 0.f; }
  __syncthreads();

  const int o = t & 63;
  const float bo = b[o];
  float lsum = 0.f, lsq = 0.f;
  for (long idx = (long)blockIdx.x * blockDim.x + threadIdx.x; idx < (long)NN * 64;
       idx += (long)gridDim.x * blockDim.x) {
    int n = (int)(idx >> 6);
    float v = fmaf(agg[idx], inv[n], bo);
    v = fmaxf(v, 0.f);
    y[idx] = v;
    lsum += v;
    lsq = fmaf(v, v, lsq);
  }
  atomicAdd(&ssum[o], lsum);
  atomicAdd(&ssq[o], lsq);
  __syncthreads();
  if (t < 64) {
    atomicAdd(&stats[t], ssum[t]);
    atomicAdd(&stats[64 + t], ssq[t]);
  }
}

__global__ void k_bn(const float* __restrict__ y, const float* __restrict__ stats,
                     const float* __restrict__ g, const float* __restrict__ be,
                     float* __restrict__ out) {
  long idx = (long)blockIdx.x * blockDim.x + threadIdx.x;
  if (idx >= (long)NN * 64) return;
  int o = (int)(idx & 63);
  float m = stats[o] * (1.0f / NN);
  float v = stats[64 + o] * (1.0f / NN) - m * m;
  out[idx] = fmaf(g[o] * rsqrtf(v + 1e-5f), y[idx] - m, be[o]);
}

__global__ void k_final(const float* __restrict__ agg, const float* __restrict__ inv,
                        const float* __restrict__ b, float* __restrict__ out) {
  long idx = (long)blockIdx.x * blockDim.x + threadIdx.x;
  if (idx >= (long)NN * 32) return;
  int n = (int)(idx >> 5);
  int o = (int)(idx & 31);
  out[idx] = fmaf(agg[idx], inv[n], b[o]);
}

// ---------------------------------------------------------------------------
extern "C" void kernel_launch(void* const* d_in, const int* in_sizes, int n_in,
                              void* d_out, int out_size, void* d_ws, size_t ws_size,
                              hipStream_t stream) {
  const float* x   = (const float*)d_in[0];
  const int*   src = (const int*)d_in[1];
  const int*   dst = src + NE;
  const float* W1 = (const float*)d_in[2];
  const float* U1 = (const float*)d_in[3];
  const float* c1 = (const float*)d_in[4];
  const float* b1 = (const float*)d_in[5];
  const float* g1 = (const float*)d_in[6];
  const float* be1 = (const float*)d_in[7];
  const float* W2 = (const float*)d_in[8];
  const float* U2 = (const float*)d_in[9];
  const float* c2 = (const float*)d_in[10];
  const float* b2 = (const float*)d_in[11];
  const float* g2 = (const float*)d_in[12];
  const float* be2 = (const float*)d_in[13];
  const float* W3 = (const float*)d_in[14];
  const float* U3 = (const float*)d_in[15];
  const float* c3 = (const float*)d_in[16];
  const float* b3 = (const float*)d_in[17];
  float* out = (float*)d_out;

  // workspace layout (floats)
  float* ws   = (float*)d_ws;
  float* inv  = ws;                 // N
  float* q    = inv + NN;           // N*8
  float* P    = q + (size_t)NN * 8; // N*512
  float* agg  = P + (size_t)NN * 512;  // N*64
  float* h1   = agg + (size_t)NN * 64; // N*64
  float* h2   = h1 + (size_t)NN * 64;  // N*64
  float* stats = h2 + (size_t)NN * 64; // 128

  const int BLK = 256;
  dim3 b256(BLK);

  // degree
  hipMemsetAsync(inv, 0, (size_t)NN * 4, stream);
  k_count<<<dim3((NE + BLK - 1) / BLK), b256, 0, stream>>>(dst, inv);
  k_inv<<<dim3((NN + BLK - 1) / BLK), b256, 0, stream>>>(inv);

  const int gemm_grid = (NN + 63) / 64;
  const int edge_grid64 = (E2 + 3) / 4;    // 4 edges/block (1 per wave)
  const int edge_grid32 = (E2 + 7) / 8;    // 8 edges/block (2 per wave)

  // ---- layer 1: x -> h1 ----
  hipMemsetAsync(agg, 0, (size_t)NN * 64 * 4, stream);
  hipMemsetAsync(stats, 0, 128 * 4, stream);
  k_gemm_xwt<512><<<dim3(gemm_grid), b256, 0, stream>>>(x, W1, P);
  k_gemm_xwt<8><<<dim3(gemm_grid), b256, 0, stream>>>(x, U1, q);
  k_edge<64><<<dim3(edge_grid64), b256, 0, stream>>>(src, dst, q, c1, P, agg);
  k_finalize_relu<<<dim3(1024), b256, 0, stream>>>(agg, inv, b1, h1, stats);
  k_bn<<<dim3(((size_t)NN * 64 + BLK - 1) / BLK), b256, 0, stream>>>(h1, stats, g1, be1, h1);

  // ---- layer 2: h1 -> h2 ----
  hipMemsetAsync(agg, 0, (size_t)NN * 64 * 4, stream);
  hipMemsetAsync(stats, 0, 128 * 4, stream);
  k_gemm_xwt<512><<<dim3(gemm_grid), b256, 0, stream>>>(h1, W2, P);
  k_gemm_xwt<8><<<dim3(gemm_grid), b256, 0, stream>>>(h1, U2, q);
  k_edge<64><<<dim3(edge_grid64), b256, 0, stream>>>(src, dst, q, c2, P, agg);
  k_finalize_relu<<<dim3(1024), b256, 0, stream>>>(agg, inv, b2, h2, stats);
  k_bn<<<dim3(((size_t)NN * 64 + BLK - 1) / BLK), b256, 0, stream>>>(h2, stats, g2, be2, h2);

  // ---- layer 3: h2 -> out ----
  hipMemsetAsync(agg, 0, (size_t)NN * 32 * 4, stream);
  k_gemm_xwt<256><<<dim3(gemm_grid), b256, 0, stream>>>(h2, W3, P);
  k_gemm_xwt<8><<<dim3(gemm_grid), b256, 0, stream>>>(h2, U3, q);
  k_edge<32><<<dim3(edge_grid32), b256, 0, stream>>>(src, dst, q, c3, P, agg);
  k_final<<<dim3(((size_t)NN * 32 + BLK - 1) / BLK), b256, 0, stream>>>(agg, inv, b3, out);
}

// Round 2
// 808.699 us; speedup vs baseline: 3.9291x; 3.9291x over previous
//
#include <hip/hip_runtime.h>
#include <hip/hip_bf16.h>
#include <math.h>

constexpr int NN = 50000;   // nodes
constexpr int NE = 800000;  // edges (without self loops)
constexpr int E2 = NE + NN; // with self loops
constexpr int NH = 8;       // heads

typedef __attribute__((ext_vector_type(8))) short bf16x8;
typedef __attribute__((ext_vector_type(4))) float f32x4;

// ---------------------------------------------------------------------------
// degree count (real edges only; self-loop added in k_inv)
__global__ void k_count(const int* __restrict__ dst, float* __restrict__ cnt) {
  int i = blockIdx.x * blockDim.x + threadIdx.x;
  if (i < NE) atomicAdd(&cnt[dst[i]], 1.0f);
}

__global__ void k_inv(float* __restrict__ inv) {
  int i = blockIdx.x * blockDim.x + threadIdx.x;
  if (i < NN) inv[i] = 1.0f / (inv[i] + 1.0f);
}

// ---------------------------------------------------------------------------
// fp32 -> bf16 conversion, 4 elements/thread (n must be multiple of 4)
__global__ void k_f2b(const float* __restrict__ in, __hip_bfloat16* __restrict__ out,
                      long n4) {
  long i = (long)blockIdx.x * blockDim.x + threadIdx.x;
  if (i >= n4) return;
  float4 v = reinterpret_cast<const float4*>(in)[i];
  ushort4 o;
  o.x = __hip_bfloat16_raw(__float2bfloat16(v.x)).x;
  o.y = __hip_bfloat16_raw(__float2bfloat16(v.y)).x;
  o.z = __hip_bfloat16_raw(__float2bfloat16(v.z)).x;
  o.w = __hip_bfloat16_raw(__float2bfloat16(v.w)).x;
  reinterpret_cast<ushort4*>(out)[i] = o;
}

// ---------------------------------------------------------------------------
// q[n,h] = sum_c X[n,c] * U[h,c]   (fp32, tiny)
__global__ void k_q(const float* __restrict__ X, const float* __restrict__ U,
                    float* __restrict__ q) {
  int n = blockIdx.x * blockDim.x + threadIdx.x;
  if (n >= NN) return;
  float4 xr[16];
  const float4* X4 = reinterpret_cast<const float4*>(X) + (size_t)n * 16;
#pragma unroll
  for (int i = 0; i < 16; ++i) xr[i] = X4[i];
  const float4* U4 = reinterpret_cast<const float4*>(U);
#pragma unroll
  for (int h = 0; h < 8; ++h) {
    float a = 0.f;
#pragma unroll
    for (int i = 0; i < 16; ++i) {
      float4 u = U4[h * 16 + i];
      a = fmaf(xr[i].x, u.x, a);
      a = fmaf(xr[i].y, u.y, a);
      a = fmaf(xr[i].z, u.z, a);
      a = fmaf(xr[i].w, u.w, a);
    }
    q[(size_t)n * 8 + h] = a;
  }
}

// ---------------------------------------------------------------------------
// P[n, j] = sum_c Xb[n,c] * Wb[j,c]  via MFMA bf16 (K=64 -> 2 k-steps of 32)
// One wave owns a 64(m) x 64(n) tile; JDIM/64 waves per block cover all j.
// A frag: lane provides A[m = 16*mi + (l&15)][k = kk*32 + (l>>4)*8 + i]
// B frag: lane provides B[k][j = 16*ni + (l&15)]  (same pattern on row-major W)
// C/D:    reg i -> row (l>>4)*4 + i, col l&15     [verified layout, m89/m91]
template <int JDIM>
__global__ void __launch_bounds__(JDIM / 64 * 64)
k_mfma_gemm(const __hip_bfloat16* __restrict__ Xb,
            const __hip_bfloat16* __restrict__ Wb,
            __hip_bfloat16* __restrict__ Pb) {
  const int lane = threadIdx.x & 63;
  const int w = threadIdx.x >> 6;  // wave id -> n tile
  const int m0 = blockIdx.x * 64;
  const int n0 = w * 64;
  const int lr = lane & 15;
  const int lk = lane >> 4;

  const ushort* X = reinterpret_cast<const ushort*>(Xb);
  const ushort* W = reinterpret_cast<const ushort*>(Wb);

  bf16x8 bfr[4][2];
#pragma unroll
  for (int ni = 0; ni < 4; ++ni)
#pragma unroll
    for (int kk = 0; kk < 2; ++kk) {
      int j = n0 + ni * 16 + lr;
      bfr[ni][kk] = *reinterpret_cast<const bf16x8*>(W + (size_t)j * 64 + kk * 32 + lk * 8);
    }

  bf16x8 afr[4][2];
#pragma unroll
  for (int mi = 0; mi < 4; ++mi)
#pragma unroll
    for (int kk = 0; kk < 2; ++kk) {
      int r = m0 + mi * 16 + lr;
      if (r >= NN) r = NN - 1;  // clamp; results discarded by store guard
      afr[mi][kk] = *reinterpret_cast<const bf16x8*>(X + (size_t)r * 64 + kk * 32 + lk * 8);
    }

  f32x4 acc[4][4] = {};
#pragma unroll
  for (int mi = 0; mi < 4; ++mi)
#pragma unroll
    for (int ni = 0; ni < 4; ++ni)
#pragma unroll
      for (int kk = 0; kk < 2; ++kk)
        acc[mi][ni] = __builtin_amdgcn_mfma_f32_16x16x32_bf16(
            afr[mi][kk], bfr[ni][kk], acc[mi][ni], 0, 0, 0);

#pragma unroll
  for (int mi = 0; mi < 4; ++mi) {
#pragma unroll
    for (int i = 0; i < 4; ++i) {
      int r = m0 + mi * 16 + lk * 4 + i;
      if (r < NN) {
#pragma unroll
        for (int ni = 0; ni < 4; ++ni) {
          int j = n0 + ni * 16 + lr;
          Pb[(size_t)r * JDIM + j] = __float2bfloat16(acc[mi][ni][i]);
        }
      }
    }
  }
}

// ---------------------------------------------------------------------------
// per-edge: softmax over heads, msg = sum_h a_h * Pb[src, h, :], scatter-add.
template <int COUT>
__global__ void k_edge(const int* __restrict__ src, const int* __restrict__ dst,
                       const float* __restrict__ q, const float* __restrict__ cvec,
                       const __hip_bfloat16* __restrict__ Pb, float* __restrict__ agg) {
  const int lane = threadIdx.x & 63;
  const long wid = ((long)blockIdx.x * blockDim.x + threadIdx.x) >> 6;
  const long e = wid * (64 / COUT) + (COUT == 64 ? 0 : (lane >> 5));
  const int o = lane & (COUT - 1);
  if (e >= E2) return;

  int s, d;
  if (e < NE) { s = src[e]; d = dst[e]; }
  else        { s = d = (int)(e - NE); }

  const float4* q4 = reinterpret_cast<const float4*>(q);
  const float4* c4p = reinterpret_cast<const float4*>(cvec);
  float4 qd0 = q4[2 * d], qd1 = q4[2 * d + 1];
  float4 qs0 = q4[2 * s], qs1 = q4[2 * s + 1];
  float4 c0 = c4p[0], c1 = c4p[1];

  float l[8];
  l[0] = qd0.x - qs0.x + c0.x;  l[1] = qd0.y - qs0.y + c0.y;
  l[2] = qd0.z - qs0.z + c0.z;  l[3] = qd0.w - qs0.w + c0.w;
  l[4] = qd1.x - qs1.x + c1.x;  l[5] = qd1.y - qs1.y + c1.y;
  l[6] = qd1.z - qs1.z + c1.z;  l[7] = qd1.w - qs1.w + c1.w;

  float m = l[0];
#pragma unroll
  for (int h = 1; h < 8; ++h) m = fmaxf(m, l[h]);
  float sum = 0.f;
#pragma unroll
  for (int h = 0; h < 8; ++h) { l[h] = __expf(l[h] - m); sum += l[h]; }
  const float inv_s = 1.0f / sum;

  const __hip_bfloat16* Prow = Pb + (size_t)s * (NH * COUT) + o;
  float acc = 0.f;
#pragma unroll
  for (int h = 0; h < 8; ++h) acc = fmaf(l[h], __bfloat162float(Prow[h * COUT]), acc);
  acc *= inv_s;

  atomicAdd(&agg[(size_t)d * COUT + o], acc);
}

// ---------------------------------------------------------------------------
// y = relu(agg*inv + b); accumulate per-channel sum/sumsq into stats
__global__ void k_finalize_relu(const float* __restrict__ agg, const float* __restrict__ inv,
                                const float* __restrict__ b, float* __restrict__ y,
                                float* __restrict__ stats) {
  __shared__ float ssum[64], ssq[64];
  const int t = threadIdx.x;
  if (t < 64) { ssum[t] = 0.f; ssq[t] = 0.f; }
  __syncthreads();

  const int o = t & 63;
  const float bo = b[o];
  float lsum = 0.f, lsq = 0.f;
  for (long idx = (long)blockIdx.x * blockDim.x + threadIdx.x; idx < (long)NN * 64;
       idx += (long)gridDim.x * blockDim.x) {
    int n = (int)(idx >> 6);
    float v = fmaf(agg[idx], inv[n], bo);
    v = fmaxf(v, 0.f);
    y[idx] = v;
    lsum += v;
    lsq = fmaf(v, v, lsq);
  }
  atomicAdd(&ssum[o], lsum);
  atomicAdd(&ssq[o], lsq);
  __syncthreads();
  if (t < 64) {
    atomicAdd(&stats[t], ssum[t]);
    atomicAdd(&stats[64 + t], ssq[t]);
  }
}

// BN: reads y (fp32), writes h (fp32, for next layer's q) and hb (bf16, for MFMA)
__global__ void k_bn(const float* __restrict__ y, const float* __restrict__ stats,
                     const float* __restrict__ g, const float* __restrict__ be,
                     float* __restrict__ h, __hip_bfloat16* __restrict__ hb) {
  long idx = (long)blockIdx.x * blockDim.x + threadIdx.x;
  if (idx >= (long)NN * 64) return;
  int o = (int)(idx & 63);
  float m = stats[o] * (1.0f / NN);
  float v = stats[64 + o] * (1.0f / NN) - m * m;
  float r = fmaf(g[o] * rsqrtf(v + 1e-5f), y[idx] - m, be[o]);
  h[idx] = r;
  hb[idx] = __float2bfloat16(r);
}

__global__ void k_final(const float* __restrict__ agg, const float* __restrict__ inv,
                        const float* __restrict__ b, float* __restrict__ out) {
  long idx = (long)blockIdx.x * blockDim.x + threadIdx.x;
  if (idx >= (long)NN * 32) return;
  int n = (int)(idx >> 5);
  int o = (int)(idx & 31);
  out[idx] = fmaf(agg[idx], inv[n], b[o]);
}

// ---------------------------------------------------------------------------
extern "C" void kernel_launch(void* const* d_in, const int* in_sizes, int n_in,
                              void* d_out, int out_size, void* d_ws, size_t ws_size,
                              hipStream_t stream) {
  const float* x   = (const float*)d_in[0];
  const int*   src = (const int*)d_in[1];
  const int*   dst = src + NE;
  const float* W1 = (const float*)d_in[2];
  const float* U1 = (const float*)d_in[3];
  const float* c1 = (const float*)d_in[4];
  const float* b1 = (const float*)d_in[5];
  const float* g1 = (const float*)d_in[6];
  const float* be1 = (const float*)d_in[7];
  const float* W2 = (const float*)d_in[8];
  const float* U2 = (const float*)d_in[9];
  const float* c2 = (const float*)d_in[10];
  const float* b2 = (const float*)d_in[11];
  const float* g2 = (const float*)d_in[12];
  const float* be2 = (const float*)d_in[13];
  const float* W3 = (const float*)d_in[14];
  const float* U3 = (const float*)d_in[15];
  const float* c3 = (const float*)d_in[16];
  const float* b3 = (const float*)d_in[17];
  float* out = (float*)d_out;

  // workspace layout (float-equivalents)
  float* ws   = (float*)d_ws;
  float* inv  = ws;                        // N
  float* q    = inv + NN;                  // N*8
  float* agg  = q + (size_t)NN * 8;        // N*64
  float* h    = agg + (size_t)NN * 64;     // N*64
  float* stats = h + (size_t)NN * 64;      // 128
  __hip_bfloat16* xb = (__hip_bfloat16*)(stats + 128);           // N*64 bf16
  __hip_bfloat16* Wb = xb + (size_t)NN * 64;                     // 512*64 bf16
  __hip_bfloat16* Pb = Wb + 512 * 64;                            // N*512 bf16

  const int BLK = 256;
  dim3 b256(BLK);

  // degree
  hipMemsetAsync(inv, 0, (size_t)NN * 4, stream);
  k_count<<<dim3((NE + BLK - 1) / BLK), b256, 0, stream>>>(dst, inv);
  k_inv<<<dim3((NN + BLK - 1) / BLK), b256, 0, stream>>>(inv);

  const int qgrid = (NN + BLK - 1) / BLK;
  const int mfma_grid = (NN + 63) / 64;            // 782
  const int edge_grid64 = (E2 + 3) / 4;            // 1 edge per wave
  const int edge_grid32 = (E2 + 7) / 8;            // 2 edges per wave
  const long xb4 = (long)NN * 64 / 4;
  const long wb4_512 = 512 * 64 / 4;

  // ---- layer 1: x -> h ----
  k_f2b<<<dim3((xb4 + BLK - 1) / BLK), b256, 0, stream>>>(x, xb, xb4);
  k_f2b<<<dim3((wb4_512 + BLK - 1) / BLK), b256, 0, stream>>>(W1, Wb, wb4_512);
  k_q<<<dim3(qgrid), b256, 0, stream>>>(x, U1, q);
  k_mfma_gemm<512><<<dim3(mfma_grid), dim3(512), 0, stream>>>(xb, Wb, Pb);
  hipMemsetAsync(agg, 0, (size_t)NN * 64 * 4, stream);
  hipMemsetAsync(stats, 0, 128 * 4, stream);
  k_edge<64><<<dim3(edge_grid64), b256, 0, stream>>>(src, dst, q, c1, Pb, agg);
  k_finalize_relu<<<dim3(1024), b256, 0, stream>>>(agg, inv, b1, h, stats);
  k_bn<<<dim3(((size_t)NN * 64 + BLK - 1) / BLK), b256, 0, stream>>>(h, stats, g1, be1, h, xb);

  // ---- layer 2: h -> h ----
  k_f2b<<<dim3((wb4_512 + BLK - 1) / BLK), b256, 0, stream>>>(W2, Wb, wb4_512);
  k_q<<<dim3(qgrid), b256, 0, stream>>>(h, U2, q);
  k_mfma_gemm<512><<<dim3(mfma_grid), dim3(512), 0, stream>>>(xb, Wb, Pb);
  hipMemsetAsync(agg, 0, (size_t)NN * 64 * 4, stream);
  hipMemsetAsync(stats, 0, 128 * 4, stream);
  k_edge<64><<<dim3(edge_grid64), b256, 0, stream>>>(src, dst, q, c2, Pb, agg);
  k_finalize_relu<<<dim3(1024), b256, 0, stream>>>(agg, inv, b2, h, stats);
  k_bn<<<dim3(((size_t)NN * 64 + BLK - 1) / BLK), b256, 0, stream>>>(h, stats, g2, be2, h, xb);

  // ---- layer 3: h -> out ----
  const long wb4_256 = 256 * 64 / 4;
  k_f2b<<<dim3((wb4_256 + BLK - 1) / BLK), b256, 0, stream>>>(W3, Wb, wb4_256);
  k_q<<<dim3(qgrid), b256, 0, stream>>>(h, U3, q);
  k_mfma_gemm<256><<<dim3(mfma_grid), dim3(256), 0, stream>>>(xb, Wb, Pb);
  hipMemsetAsync(agg, 0, (size_t)NN * 32 * 4, stream);
  k_edge<32><<<dim3(edge_grid32), b256, 0, stream>>>(src, dst, q, c3, Pb, agg);
  k_final<<<dim3(((size_t)NN * 32 + BLK - 1) / BLK), b256, 0, stream>>>(agg, inv, b3, out);
}